// Round 7
// baseline (478.671 us; speedup 1.0000x reference)
//
#include <hip/hip_runtime.h>

// out = x + Ax + A^2 x + A^3 x
// R6: R5 fully reverted (perm degree-sort +32% dur regression: scattered the sequential
//     csr/h/epilogue streams; NT loads on scattered reads amplified FETCH +23MB).
//     Gathers restored to R4 exactly (8-edge unroll, normal loads, 75.4us measured).
// R6 new lever: direct-placement CSR build replaces 2-level counting sort.
//     old: cvt_hist -> pass1 (scatter 12.8MB staging) -> pass2 (read back + scatter csr)
//     new: cvt_hist (+ per-row global hist, 400KB L2-resident)
//          -> rowstart_kernel (redundant bucket scan + per-bucket LDS row scan)
//          -> scatter_kernel (csr[rowstart[r] + atomicAdd(rowCur[r])] directly)
//     Deletes the 25.6MB staging round-trip and one full sorting pass.
// N=100000, D=100, E=1600000, layer_num=3 (fixed by setup_inputs)

#define NODES 100000
#define DIM 100
#define DIM4 25                        // float4 chunks per compact fp32 row
#define CH 16                          // 16B fp16 chunks per padded row (128 halves, 256 B)
#define BSHIFT 8
#define NBUCKETS ((NODES + 255) >> 8)  // 391 buckets of 256 rows
#define NPAD (NBUCKETS << BSHIFT)      // 100096

typedef _Float16 half4_t __attribute__((ext_vector_type(4)));
typedef _Float16 half8_t __attribute__((ext_vector_type(8)));

// fused: fp32 compact [N][100] -> fp16 padded [N][128]  +  per-row global hist
//        + per-bucket LDS hist (bucket sums feed rowstart_kernel's base scan)
__global__ void cvt_hist_kernel(const float4* __restrict__ emb, half4_t* __restrict__ x0,
                                const int* __restrict__ rows, int* __restrict__ rowCnt,
                                int* __restrict__ bktCount, int E) {
    __shared__ int h[NBUCKETS];
    for (int i = threadIdx.x; i < NBUCKETS; i += blockDim.x) h[i] = 0;
    __syncthreads();
    int stride = gridDim.x * blockDim.x;
    int gid = blockIdx.x * blockDim.x + threadIdx.x;
    for (int i = gid; i < NODES * 32; i += stride) {
        int r = i >> 5, c = i & 31;
        half4_t hv;
        if (c < 25) {
            float4 f = emb[r * 25 + c];
            hv.x = (_Float16)f.x; hv.y = (_Float16)f.y;
            hv.z = (_Float16)f.z; hv.w = (_Float16)f.w;
        } else {
            hv.x = (_Float16)0.f; hv.y = (_Float16)0.f;
            hv.z = (_Float16)0.f; hv.w = (_Float16)0.f;
        }
        x0[i] = hv;
    }
    for (int e = gid; e < E; e += stride) {
        int r = rows[e];
        atomicAdd(&rowCnt[r], 1);          // 400KB table, L2-resident
        atomicAdd(&h[r >> BSHIFT], 1);     // LDS bucket hist
    }
    __syncthreads();
    for (int i = threadIdx.x; i < NBUCKETS; i += blockDim.x)
        if (h[i]) atomicAdd(&bktCount[i], h[i]);
}

// one block per bucket (512 thr): redundant exclusive scan of the 391 bucket counts
// (proven pass1 trick, L2-hot 1.5KB) -> bucket base; LDS scan of the bucket's 256
// rowCnt entries -> global rowstart. Ghost rows (>=NODES) have cnt 0.
// Max index gathers read is rowstart[100000] = bucket 390, t=160 -> covered.
__global__ void rowstart_kernel(const int* __restrict__ bktCount,
                                const int* __restrict__ rowCnt,
                                int* __restrict__ rowstart) {
    __shared__ int sc[512];
    __shared__ int rs[256];
    __shared__ int sbase;
    int b = blockIdx.x, t = threadIdx.x;
    int v = (t < NBUCKETS) ? bktCount[t] : 0;
    sc[t] = v;
    __syncthreads();
    for (int off = 1; off < 512; off <<= 1) {
        int x = (t >= off) ? sc[t - off] : 0;
        __syncthreads();
        sc[t] += x;
        __syncthreads();
    }
    if (t == b) sbase = sc[t] - v;                  // exclusive base of own bucket
    int rv = (t < 256) ? rowCnt[(b << BSHIFT) + t] : 0;
    if (t < 256) rs[t] = rv;
    __syncthreads();
    for (int off = 1; off < 256; off <<= 1) {
        int x = (t >= off && t < 256) ? rs[t - off] : 0;
        __syncthreads();
        if (t < 256) rs[t] += x;
        __syncthreads();
    }
    if (t < 256) rowstart[(b << BSHIFT) + t] = sbase + rs[t] - rv;   // exclusive
}

// direct scatter: each edge goes straight to its final CSR slot
__global__ void scatter_kernel(const int* __restrict__ rows, const int* __restrict__ cols,
                               const float* __restrict__ vals,
                               const int* __restrict__ rowstart, int* __restrict__ rowCur,
                               int2* __restrict__ csr, int E) {
    int gid = blockIdx.x * blockDim.x + threadIdx.x;
    int stride = gridDim.x * blockDim.x;
    for (int i = gid; i < E; i += stride) {
        int r = rows[i];
        int p = rowstart[r] + atomicAdd(&rowCur[r], 1);
        csr[p] = make_int2(cols[i], __float_as_int(vals[i]));
    }
}

// pull SpMM: 16 lanes per row, each loads one 16B fp16 chunk (row = 2 aligned 128-B lines)
// 8-edge unroll (R4 verified: 75.4us last-layer)
__global__ void gather_mid8_kernel(const int* __restrict__ rowstart,
                                   const int2* __restrict__ csr,
                                   const half8_t* __restrict__ x,
                                   half8_t* __restrict__ h) {
    int gid = blockIdx.x * blockDim.x + threadIdx.x;
    int row = gid >> 4, lane = gid & 15;
    if (row >= NODES) return;
    int s = rowstart[row], e = rowstart[row + 1];
    float acc[8] = {0.f, 0.f, 0.f, 0.f, 0.f, 0.f, 0.f, 0.f};
    int i = s;
    for (; i + 7 < e; i += 8) {
        int2 rr[8];
        #pragma unroll
        for (int j = 0; j < 8; ++j) rr[j] = csr[i + j];
        half8_t aa[8];
        #pragma unroll
        for (int j = 0; j < 8; ++j) aa[j] = x[((size_t)rr[j].x << 4) + lane];
        #pragma unroll
        for (int j = 0; j < 8; ++j) {
            float v = __int_as_float(rr[j].y);
            #pragma unroll
            for (int k = 0; k < 8; ++k) acc[k] += v * (float)aa[j][k];
        }
    }
    for (; i < e; ++i) {
        int2 r0 = csr[i];
        half8_t a0 = x[((size_t)r0.x << 4) + lane];
        float v0 = __int_as_float(r0.y);
        #pragma unroll
        for (int k = 0; k < 8; ++k) acc[k] += v0 * (float)a0[k];
    }
    half8_t hv;
    #pragma unroll
    for (int k = 0; k < 8; ++k) hv[k] = (_Float16)acc[k];
    h[((size_t)row << 4) + lane] = hv;
}

// last layer: fused epilogue out = fp16(x) + h1 + h2 + acc; 8-edge unroll
__global__ void gather_last_kernel(const int* __restrict__ rowstart,
                                   const int2* __restrict__ csr,
                                   const half8_t* __restrict__ x,      // h2 (gather operand)
                                   const half8_t* __restrict__ x0,
                                   const half8_t* __restrict__ h1,
                                   const half8_t* __restrict__ h2,
                                   float4* __restrict__ out) {
    int gid = blockIdx.x * blockDim.x + threadIdx.x;
    int row = gid >> 4, lane = gid & 15;
    if (row >= NODES) return;
    int s = rowstart[row], e = rowstart[row + 1];
    float acc[8] = {0.f, 0.f, 0.f, 0.f, 0.f, 0.f, 0.f, 0.f};
    int i = s;
    for (; i + 7 < e; i += 8) {
        int2 rr[8];
        #pragma unroll
        for (int j = 0; j < 8; ++j) rr[j] = csr[i + j];
        half8_t aa[8];
        #pragma unroll
        for (int j = 0; j < 8; ++j) aa[j] = x[((size_t)rr[j].x << 4) + lane];
        #pragma unroll
        for (int j = 0; j < 8; ++j) {
            float v = __int_as_float(rr[j].y);
            #pragma unroll
            for (int k = 0; k < 8; ++k) acc[k] += v * (float)aa[j][k];
        }
    }
    for (; i < e; ++i) {
        int2 r0 = csr[i];
        half8_t a0 = x[((size_t)r0.x << 4) + lane];
        float v0 = __int_as_float(r0.y);
        #pragma unroll
        for (int k = 0; k < 8; ++k) acc[k] += v0 * (float)a0[k];
    }
    size_t pidx = ((size_t)row << 4) + lane;
    half8_t xe = x0[pidx], a1 = h1[pidx], a2 = h2[pidx];
    int f4 = row * DIM4 + lane * 2;                  // features lane*8 .. lane*8+7
    if (lane < 13) {
        float4 o0;
        o0.x = acc[0] + (float)xe[0] + (float)a1[0] + (float)a2[0];
        o0.y = acc[1] + (float)xe[1] + (float)a1[1] + (float)a2[1];
        o0.z = acc[2] + (float)xe[2] + (float)a1[2] + (float)a2[2];
        o0.w = acc[3] + (float)xe[3] + (float)a1[3] + (float)a2[3];
        out[f4] = o0;
    }
    if (lane < 12) {                                 // lane 12 covers only feats 96..99
        float4 o1;
        o1.x = acc[4] + (float)xe[4] + (float)a1[4] + (float)a2[4];
        o1.y = acc[5] + (float)xe[5] + (float)a1[5] + (float)a2[5];
        o1.z = acc[6] + (float)xe[6] + (float)a1[6] + (float)a2[6];
        o1.w = acc[7] + (float)xe[7] + (float)a1[7] + (float)a2[7];
        out[f4 + 1] = o1;
    }
}

extern "C" void kernel_launch(void* const* d_in, const int* in_sizes, int n_in,
                              void* d_out, int out_size, void* d_ws, size_t ws_size,
                              hipStream_t stream) {
    const float* emb  = (const float*)d_in[0];
    const int*   rows = (const int*)  d_in[1];
    const int*   cols = (const int*)  d_in[2];
    const float* vals = (const float*)d_in[3];
    const int E = in_sizes[1];

    const size_t ndp_bytes = (size_t)NODES * 128 * sizeof(_Float16);   // 25.6 MB padded

    char* w = (char*)d_ws;
    half8_t* x0p      = (half8_t*)w;  w += ndp_bytes;
    half8_t* h1p      = (half8_t*)w;  w += ndp_bytes;
    half8_t* h2p      = (half8_t*)w;  w += ndp_bytes;
    int2*    csr      = (int2*)   w;  w += (size_t)E * sizeof(int2);   // 12.8 MB
    int*     rowstart = (int*)    w;  w += (size_t)(NPAD + 8) * sizeof(int);
    int*     rowCnt   = (int*)    w;  w += (size_t)NPAD * sizeof(int); // -- contiguous
    int*     rowCur   = (int*)    w;  w += (size_t)NPAD * sizeof(int); //    memset zone
    int*     bktCount = (int*)    w;  w += 512 * sizeof(int);          // --
    // total ~91.0 MB

    float4* out = (float4*)d_out;

    // ---- build CSR (direct placement) ----
    hipMemsetAsync(rowCnt, 0, (size_t)(2 * NPAD + 512) * sizeof(int), stream);
    cvt_hist_kernel<<<1024, 256, 0, stream>>>((const float4*)emb, (half4_t*)x0p,
                                              rows, rowCnt, bktCount, E);
    rowstart_kernel<<<NBUCKETS, 512, 0, stream>>>(bktCount, rowCnt, rowstart);
    scatter_kernel<<<2048, 256, 0, stream>>>(rows, cols, vals, rowstart, rowCur, csr, E);

    // ---- 3 gather SpMM layers; last one fuses the output combine ----
    const long long threads = (long long)NODES * 16;
    dim3 gGrid((unsigned)((threads + 255) / 256)), gBlock(256);
    gather_mid8_kernel<<<gGrid, gBlock, 0, stream>>>(rowstart, csr, x0p, h1p);
    gather_mid8_kernel<<<gGrid, gBlock, 0, stream>>>(rowstart, csr, h1p, h2p);
    gather_last_kernel<<<gGrid, gBlock, 0, stream>>>(rowstart, csr, h2p, x0p, h1p, h2p, out);
}

// Round 8
// 371.045 us; speedup vs baseline: 1.2901x; 1.2901x over previous
//
#include <hip/hip_runtime.h>

// out = x + Ax + A^2 x + A^3 x
// Build: 2-level counting sort (391 buckets x 256 rows) -> row-grouped CSR (R4-verified;
//   R6's direct-placement scatter was +115us: 8x write amplification, WRITE 101MB for
//   12.8MB csr. Scatter confinement to 64KB bucket windows is the build's key property.)
// SpMM: pull gather, fp16 rows padded to 256 B (16 x 16B chunks, line-aligned), but
//   only lanes 0..12 active (R8): lanes 13-15 fetched pure padding = 19% wasted
//   vector-memory requests. Pad chunks of h1/h2 never written, never read.
// N=100000, D=100, E=1600000, layer_num=3 (fixed by setup_inputs)

#define NODES 100000
#define DIM 100
#define DIM4 25                        // float4 chunks per compact fp32 row
#define CH 16                          // 16B fp16 chunks per padded row (128 halves, 256 B)
#define BSHIFT 8
#define NBUCKETS ((NODES + 255) >> 8)  // 391 buckets of 256 rows
#define NPAD (NBUCKETS << BSHIFT)      // 100096

typedef _Float16 half4_t __attribute__((ext_vector_type(4)));
typedef _Float16 half8_t __attribute__((ext_vector_type(8)));

// fused: fp32 compact [N][100] -> fp16 padded [N][128]  +  bucket histogram
__global__ void cvt_hist_kernel(const float4* __restrict__ emb, half4_t* __restrict__ x0,
                                const int* __restrict__ rows, int* __restrict__ bktCount, int E) {
    __shared__ int h[NBUCKETS];
    for (int i = threadIdx.x; i < NBUCKETS; i += blockDim.x) h[i] = 0;
    __syncthreads();
    int stride = gridDim.x * blockDim.x;
    int gid = blockIdx.x * blockDim.x + threadIdx.x;
    for (int i = gid; i < NODES * 32; i += stride) {
        int r = i >> 5, c = i & 31;
        half4_t hv;
        if (c < 25) {
            float4 f = emb[r * 25 + c];
            hv.x = (_Float16)f.x; hv.y = (_Float16)f.y;
            hv.z = (_Float16)f.z; hv.w = (_Float16)f.w;
        } else {
            hv.x = (_Float16)0.f; hv.y = (_Float16)0.f;
            hv.z = (_Float16)0.f; hv.w = (_Float16)0.f;
        }
        x0[i] = hv;
    }
    for (int e = gid; e < E; e += stride)
        atomicAdd(&h[rows[e] >> BSHIFT], 1);
    __syncthreads();
    for (int i = threadIdx.x; i < NBUCKETS; i += blockDim.x)
        if (h[i]) atomicAdd(&bktCount[i], h[i]);
}

// pass 1 (512 thr): count own chunk; redundant LDS scan of global bucket counts;
// claim contiguous region per (block,bucket) via zero-init global cursor; scatter.
// Block 0 also publishes bktStart. One dispatch replaces scan+pass1.
__global__ void pass1_kernel(const int* __restrict__ rows, const int* __restrict__ cols,
                             const float* __restrict__ vals,
                             const int* __restrict__ bktCount, int* __restrict__ gCur,
                             int* __restrict__ bktStart,
                             int2* __restrict__ staging, int E) {
    __shared__ int cnt[NBUCKETS];
    __shared__ int bst[NBUCKETS];
    __shared__ int sc[512];
    int t = threadIdx.x;
    for (int i = t; i < NBUCKETS; i += 512) cnt[i] = 0;
    __syncthreads();
    int chunk = (E + gridDim.x - 1) / gridDim.x;
    int s = blockIdx.x * chunk;
    int e = min(E, s + chunk);
    for (int i = s + t; i < e; i += 512)
        atomicAdd(&cnt[rows[i] >> BSHIFT], 1);
    // redundant exclusive scan of the 391 global bucket counts (L2-hot, 1.5 KB)
    int v = (t < NBUCKETS) ? bktCount[t] : 0;
    sc[t] = v;
    __syncthreads();
    for (int off = 1; off < 512; off <<= 1) {
        int x = (t >= off) ? sc[t - off] : 0;
        __syncthreads();
        sc[t] += x;
        __syncthreads();
    }
    int excl = sc[t] - v;
    if (blockIdx.x == 0) {
        if (t < NBUCKETS) bktStart[t] = excl;
        if (t == 0) bktStart[NBUCKETS] = E;
    }
    if (t < NBUCKETS) {
        int c = cnt[t];
        bst[t] = excl + (c ? atomicAdd(&gCur[t], c) : 0);
        cnt[t] = 0;                                 // becomes in-block cursor
    }
    __syncthreads();
    for (int i = s + t; i < e; i += 512) {
        int r = rows[i];
        int b = r >> BSHIFT;
        int pos = bst[b] + atomicAdd(&cnt[b], 1);
        staging[pos] = make_int2(cols[i] | ((r & 255) << 17), __float_as_int(vals[i]));
    }
}

// pass 2 (512 thr): per-bucket counting sort by localrow -> rowstart + CSR
__global__ void pass2_kernel(const int* __restrict__ bktStart, const int2* __restrict__ staging,
                             int* __restrict__ rowstart, int2* __restrict__ csr) {
    __shared__ int hist[256];
    __shared__ int cur[256];
    int b = blockIdx.x, t = threadIdx.x;
    int s = bktStart[b], e = bktStart[b + 1];
    if (t < 256) hist[t] = 0;
    __syncthreads();
    for (int i = s + t; i < e; i += 512)
        atomicAdd(&hist[(staging[i].x >> 17) & 255], 1);
    __syncthreads();
    int v = (t < 256) ? hist[t] : 0;
    if (t < 256) cur[t] = v;
    __syncthreads();
    for (int off = 1; off < 256; off <<= 1) {
        int x = (t >= off && t < 256) ? cur[t - off] : 0;
        __syncthreads();
        if (t < 256) cur[t] += x;
        __syncthreads();
    }
    if (t < 256) {
        int excl = cur[t] - v;
        rowstart[(b << BSHIFT) + t] = s + excl;
        hist[t] = excl;                             // becomes bucket-local cursor
    }
    __syncthreads();
    for (int i = s + t; i < e; i += 512) {
        int2 rec = staging[i];
        int lr = (rec.x >> 17) & 255;
        int p = atomicAdd(&hist[lr], 1);
        csr[s + p] = make_int2(rec.x & 0x1FFFF, rec.y);
    }
}

// pull SpMM: 13 active lanes per 16-lane row group, each loads one 16B fp16 chunk.
// 8-edge unroll. Lanes 13-15 idle (pad chunks: fetching them wasted 19% of requests).
__global__ void gather_mid8_kernel(const int* __restrict__ rowstart,
                                   const int2* __restrict__ csr,
                                   const half8_t* __restrict__ x,
                                   half8_t* __restrict__ h) {
    int gid = blockIdx.x * blockDim.x + threadIdx.x;
    int row = gid >> 4, lane = gid & 15;
    if (row >= NODES || lane >= 13) return;
    int s = rowstart[row], e = rowstart[row + 1];
    float acc[8] = {0.f, 0.f, 0.f, 0.f, 0.f, 0.f, 0.f, 0.f};
    int i = s;
    for (; i + 7 < e; i += 8) {
        int2 rr[8];
        #pragma unroll
        for (int j = 0; j < 8; ++j) rr[j] = csr[i + j];
        half8_t aa[8];
        #pragma unroll
        for (int j = 0; j < 8; ++j) aa[j] = x[((size_t)rr[j].x << 4) + lane];
        #pragma unroll
        for (int j = 0; j < 8; ++j) {
            float v = __int_as_float(rr[j].y);
            #pragma unroll
            for (int k = 0; k < 8; ++k) acc[k] += v * (float)aa[j][k];
        }
    }
    for (; i < e; ++i) {
        int2 r0 = csr[i];
        half8_t a0 = x[((size_t)r0.x << 4) + lane];
        float v0 = __int_as_float(r0.y);
        #pragma unroll
        for (int k = 0; k < 8; ++k) acc[k] += v0 * (float)a0[k];
    }
    half8_t hv;
    #pragma unroll
    for (int k = 0; k < 8; ++k) hv[k] = (_Float16)acc[k];
    h[((size_t)row << 4) + lane] = hv;
}

// last layer: fused epilogue out = fp16(x) + h1 + h2 + acc; 8-edge unroll; 13 lanes
__global__ void gather_last_kernel(const int* __restrict__ rowstart,
                                   const int2* __restrict__ csr,
                                   const half8_t* __restrict__ x,      // h2 (gather operand)
                                   const half8_t* __restrict__ x0,
                                   const half8_t* __restrict__ h1,
                                   const half8_t* __restrict__ h2,
                                   float4* __restrict__ out) {
    int gid = blockIdx.x * blockDim.x + threadIdx.x;
    int row = gid >> 4, lane = gid & 15;
    if (row >= NODES || lane >= 13) return;
    int s = rowstart[row], e = rowstart[row + 1];
    float acc[8] = {0.f, 0.f, 0.f, 0.f, 0.f, 0.f, 0.f, 0.f};
    int i = s;
    for (; i + 7 < e; i += 8) {
        int2 rr[8];
        #pragma unroll
        for (int j = 0; j < 8; ++j) rr[j] = csr[i + j];
        half8_t aa[8];
        #pragma unroll
        for (int j = 0; j < 8; ++j) aa[j] = x[((size_t)rr[j].x << 4) + lane];
        #pragma unroll
        for (int j = 0; j < 8; ++j) {
            float v = __int_as_float(rr[j].y);
            #pragma unroll
            for (int k = 0; k < 8; ++k) acc[k] += v * (float)aa[j][k];
        }
    }
    for (; i < e; ++i) {
        int2 r0 = csr[i];
        half8_t a0 = x[((size_t)r0.x << 4) + lane];
        float v0 = __int_as_float(r0.y);
        #pragma unroll
        for (int k = 0; k < 8; ++k) acc[k] += v0 * (float)a0[k];
    }
    size_t pidx = ((size_t)row << 4) + lane;
    half8_t xe = x0[pidx], a1 = h1[pidx], a2 = h2[pidx];
    int f4 = row * DIM4 + lane * 2;                  // features lane*8 .. lane*8+7
    float4 o0;
    o0.x = acc[0] + (float)xe[0] + (float)a1[0] + (float)a2[0];
    o0.y = acc[1] + (float)xe[1] + (float)a1[1] + (float)a2[1];
    o0.z = acc[2] + (float)xe[2] + (float)a1[2] + (float)a2[2];
    o0.w = acc[3] + (float)xe[3] + (float)a1[3] + (float)a2[3];
    out[f4] = o0;
    if (lane < 12) {                                 // lane 12 covers only feats 96..99
        float4 o1;
        o1.x = acc[4] + (float)xe[4] + (float)a1[4] + (float)a2[4];
        o1.y = acc[5] + (float)xe[5] + (float)a1[5] + (float)a2[5];
        o1.z = acc[6] + (float)xe[6] + (float)a1[6] + (float)a2[6];
        o1.w = acc[7] + (float)xe[7] + (float)a1[7] + (float)a2[7];
        out[f4 + 1] = o1;
    }
}

extern "C" void kernel_launch(void* const* d_in, const int* in_sizes, int n_in,
                              void* d_out, int out_size, void* d_ws, size_t ws_size,
                              hipStream_t stream) {
    const float* emb  = (const float*)d_in[0];
    const int*   rows = (const int*)  d_in[1];
    const int*   cols = (const int*)  d_in[2];
    const float* vals = (const float*)d_in[3];
    const int E = in_sizes[1];

    const size_t ndp_bytes = (size_t)NODES * 128 * sizeof(_Float16);   // 25.6 MB padded

    char* w = (char*)d_ws;
    half8_t* x0p      = (half8_t*)w;  w += ndp_bytes;
    half8_t* h1p      = (half8_t*)w;  w += ndp_bytes;
    half8_t* h2p      = (half8_t*)w;  w += ndp_bytes;                  // aliases staging
    int2*    staging  = (int2*)h2p;                                    // dead after pass2; h2p written after
    int2*    csr      = (int2*)   w;  w += (size_t)E * sizeof(int2);   // 12.8 MB
    int*     rowstart = (int*)    w;  w += (size_t)(NPAD + 256) * sizeof(int);
    int*     bktCount = (int*)    w;  w += 512 * sizeof(int);
    int*     gCur     = (int*)    w;  w += 512 * sizeof(int);          // adjacent to bktCount
    int*     bktStart = (int*)    w;  w += 512 * sizeof(int);
    // total ~90.2 MB

    float4* out = (float4*)d_out;

    // ---- build CSR ----
    hipMemsetAsync(bktCount, 0, 1024 * sizeof(int), stream);           // bktCount + gCur
    cvt_hist_kernel<<<1024, 256, 0, stream>>>((const float4*)emb, (half4_t*)x0p,
                                              rows, bktCount, E);
    pass1_kernel<<<256, 512, 0, stream>>>(rows, cols, vals, bktCount, gCur, bktStart,
                                          staging, E);
    pass2_kernel<<<NBUCKETS, 512, 0, stream>>>(bktStart, staging, rowstart, csr);

    // ---- 3 gather SpMM layers; last one fuses the output combine ----
    const long long threads = (long long)NODES * 16;
    dim3 gGrid((unsigned)((threads + 255) / 256)), gBlock(256);
    gather_mid8_kernel<<<gGrid, gBlock, 0, stream>>>(rowstart, csr, x0p, h1p);
    gather_mid8_kernel<<<gGrid, gBlock, 0, stream>>>(rowstart, csr, h1p, h2p);
    gather_last_kernel<<<gGrid, gBlock, 0, stream>>>(rowstart, csr, h2p, x0p, h1p, h2p, out);
}

// Round 9
// 366.012 us; speedup vs baseline: 1.3078x; 1.0138x over previous
//
#include <hip/hip_runtime.h>

// out = x + Ax + A^2 x + A^3 x
// Build: 2-level counting sort (391 buckets x 256 rows) -> row-grouped CSR.
//   R9: edges counted ONCE. cvt_hist counts with pass1-aligned chunks (512 blocks),
//   persists blkCnt[block][bucket]; pass1 claims from blkCnt (count pass deleted:
//   -6.4MB rows re-read, -1.6M LDS atomics). Per-block contiguous claims preserved
//   (R6 proved write confinement to 64KB bucket windows is load-bearing).
// SpMM: pull gather (R4-verified form): fp16 rows padded to 256 B (16 x 16B chunks,
//   line-aligned), 16 lanes/row. R8's lane<13 mask was null: lanes 13-15 coalesce
//   into the same 2 lines, masking saves nothing. mid4/mid8/last8 unrolls.
// Gathers pinned at 3.5-3.8 TB/s L2-miss traffic across all levers tried -> treated
// as fabric/L3 scattered-line ceiling; this round touches only the build.
// N=100000, D=100, E=1600000, layer_num=3 (fixed by setup_inputs)

#define NODES 100000
#define DIM 100
#define DIM4 25                        // float4 chunks per compact fp32 row
#define CH 16                          // 16B fp16 chunks per padded row (128 halves, 256 B)
#define BSHIFT 8
#define NBUCKETS ((NODES + 255) >> 8)  // 391 buckets of 256 rows
#define NPAD (NBUCKETS << BSHIFT)      // 100096
#define NCHUNK 512                     // shared edge-chunk count (cvt_hist & pass1 grids)

typedef _Float16 half4_t __attribute__((ext_vector_type(4)));
typedef _Float16 half8_t __attribute__((ext_vector_type(8)));

// fused: fp32 compact [N][100] -> fp16 padded [N][128]  +  chunked bucket histogram
// (blkCnt[b][k] = edges of chunk b in bucket k; bktCount = global sums)
__global__ void cvt_hist_kernel(const float4* __restrict__ emb, half4_t* __restrict__ x0,
                                const int* __restrict__ rows, int* __restrict__ blkCnt,
                                int* __restrict__ bktCount, int E) {
    __shared__ int h[NBUCKETS];
    for (int i = threadIdx.x; i < NBUCKETS; i += blockDim.x) h[i] = 0;
    __syncthreads();
    int stride = gridDim.x * blockDim.x;
    int gid = blockIdx.x * blockDim.x + threadIdx.x;
    for (int i = gid; i < NODES * 32; i += stride) {
        int r = i >> 5, c = i & 31;
        half4_t hv;
        if (c < 25) {
            float4 f = emb[r * 25 + c];
            hv.x = (_Float16)f.x; hv.y = (_Float16)f.y;
            hv.z = (_Float16)f.z; hv.w = (_Float16)f.w;
        } else {
            hv.x = (_Float16)0.f; hv.y = (_Float16)0.f;
            hv.z = (_Float16)0.f; hv.w = (_Float16)0.f;
        }
        x0[i] = hv;
    }
    // edge count over THIS block's chunk (same chunking as pass1's scatter)
    int chunk = (E + gridDim.x - 1) / gridDim.x;
    int s = blockIdx.x * chunk;
    int e = min(E, s + chunk);
    for (int i = s + threadIdx.x; i < e; i += blockDim.x)
        atomicAdd(&h[rows[i] >> BSHIFT], 1);
    __syncthreads();
    for (int i = threadIdx.x; i < NBUCKETS; i += blockDim.x) {
        blkCnt[blockIdx.x * NBUCKETS + i] = h[i];
        if (h[i]) atomicAdd(&bktCount[i], h[i]);
    }
}

// pass 1 (512 blocks x 512 thr): redundant LDS scan of global bucket counts;
// claim contiguous region per (block,bucket) via blkCnt + global cursor; scatter.
// Block 0 also publishes bktStart. Count pass deleted (R9): claims come from blkCnt.
__global__ void pass1_kernel(const int* __restrict__ rows, const int* __restrict__ cols,
                             const float* __restrict__ vals,
                             const int* __restrict__ bktCount, const int* __restrict__ blkCnt,
                             int* __restrict__ gCur, int* __restrict__ bktStart,
                             int2* __restrict__ staging, int E) {
    __shared__ int cnt[NBUCKETS];
    __shared__ int bst[NBUCKETS];
    __shared__ int sc[512];
    int t = threadIdx.x;
    // redundant exclusive scan of the 391 global bucket counts (L2-hot, 1.5 KB)
    int v = (t < NBUCKETS) ? bktCount[t] : 0;
    sc[t] = v;
    __syncthreads();
    for (int off = 1; off < 512; off <<= 1) {
        int x = (t >= off) ? sc[t - off] : 0;
        __syncthreads();
        sc[t] += x;
        __syncthreads();
    }
    int excl = sc[t] - v;
    if (blockIdx.x == 0) {
        if (t < NBUCKETS) bktStart[t] = excl;
        if (t == 0) bktStart[NBUCKETS] = E;
    }
    if (t < NBUCKETS) {
        int c = blkCnt[blockIdx.x * NBUCKETS + t];
        bst[t] = excl + (c ? atomicAdd(&gCur[t], c) : 0);
        cnt[t] = 0;                                 // in-block cursor
    }
    __syncthreads();
    int chunk = (E + gridDim.x - 1) / gridDim.x;
    int s = blockIdx.x * chunk;
    int e = min(E, s + chunk);
    for (int i = s + t; i < e; i += 512) {
        int r = rows[i];
        int b = r >> BSHIFT;
        int pos = bst[b] + atomicAdd(&cnt[b], 1);
        staging[pos] = make_int2(cols[i] | ((r & 255) << 17), __float_as_int(vals[i]));
    }
}

// pass 2 (512 thr): per-bucket counting sort by localrow -> rowstart + CSR
__global__ void pass2_kernel(const int* __restrict__ bktStart, const int2* __restrict__ staging,
                             int* __restrict__ rowstart, int2* __restrict__ csr) {
    __shared__ int hist[256];
    __shared__ int cur[256];
    int b = blockIdx.x, t = threadIdx.x;
    int s = bktStart[b], e = bktStart[b + 1];
    if (t < 256) hist[t] = 0;
    __syncthreads();
    for (int i = s + t; i < e; i += 512)
        atomicAdd(&hist[(staging[i].x >> 17) & 255], 1);
    __syncthreads();
    int v = (t < 256) ? hist[t] : 0;
    if (t < 256) cur[t] = v;
    __syncthreads();
    for (int off = 1; off < 256; off <<= 1) {
        int x = (t >= off && t < 256) ? cur[t - off] : 0;
        __syncthreads();
        if (t < 256) cur[t] += x;
        __syncthreads();
    }
    if (t < 256) {
        int excl = cur[t] - v;
        rowstart[(b << BSHIFT) + t] = s + excl;
        hist[t] = excl;                             // becomes bucket-local cursor
    }
    __syncthreads();
    for (int i = s + t; i < e; i += 512) {
        int2 rec = staging[i];
        int lr = (rec.x >> 17) & 255;
        int p = atomicAdd(&hist[lr], 1);
        csr[s + p] = make_int2(rec.x & 0x1FFFF, rec.y);
    }
}

// pull SpMM: 16 lanes per row, each loads one 16B fp16 chunk (row = 2 aligned 128-B lines)
__global__ void gather_mid4_kernel(const int* __restrict__ rowstart,
                                   const int2* __restrict__ csr,
                                   const half8_t* __restrict__ x,
                                   half8_t* __restrict__ h) {
    int gid = blockIdx.x * blockDim.x + threadIdx.x;
    int row = gid >> 4, lane = gid & 15;
    if (row >= NODES) return;
    int s = rowstart[row], e = rowstart[row + 1];
    float acc[8] = {0.f, 0.f, 0.f, 0.f, 0.f, 0.f, 0.f, 0.f};
    int i = s;
    for (; i + 3 < e; i += 4) {
        int2 r0 = csr[i], r1 = csr[i + 1], r2 = csr[i + 2], r3 = csr[i + 3];
        half8_t a0 = x[((size_t)r0.x << 4) + lane];
        half8_t a1 = x[((size_t)r1.x << 4) + lane];
        half8_t a2 = x[((size_t)r2.x << 4) + lane];
        half8_t a3 = x[((size_t)r3.x << 4) + lane];
        float v0 = __int_as_float(r0.y), v1 = __int_as_float(r1.y);
        float v2 = __int_as_float(r2.y), v3 = __int_as_float(r3.y);
        #pragma unroll
        for (int k = 0; k < 8; ++k)
            acc[k] += v0 * (float)a0[k] + v1 * (float)a1[k]
                    + v2 * (float)a2[k] + v3 * (float)a3[k];
    }
    for (; i < e; ++i) {
        int2 r0 = csr[i];
        half8_t a0 = x[((size_t)r0.x << 4) + lane];
        float v0 = __int_as_float(r0.y);
        #pragma unroll
        for (int k = 0; k < 8; ++k) acc[k] += v0 * (float)a0[k];
    }
    half8_t hv;
    #pragma unroll
    for (int k = 0; k < 8; ++k) hv[k] = (_Float16)acc[k];
    h[((size_t)row << 4) + lane] = hv;
}

// same but 8-edge unroll
__global__ void gather_mid8_kernel(const int* __restrict__ rowstart,
                                   const int2* __restrict__ csr,
                                   const half8_t* __restrict__ x,
                                   half8_t* __restrict__ h) {
    int gid = blockIdx.x * blockDim.x + threadIdx.x;
    int row = gid >> 4, lane = gid & 15;
    if (row >= NODES) return;
    int s = rowstart[row], e = rowstart[row + 1];
    float acc[8] = {0.f, 0.f, 0.f, 0.f, 0.f, 0.f, 0.f, 0.f};
    int i = s;
    for (; i + 7 < e; i += 8) {
        int2 rr[8];
        #pragma unroll
        for (int j = 0; j < 8; ++j) rr[j] = csr[i + j];
        half8_t aa[8];
        #pragma unroll
        for (int j = 0; j < 8; ++j) aa[j] = x[((size_t)rr[j].x << 4) + lane];
        #pragma unroll
        for (int j = 0; j < 8; ++j) {
            float v = __int_as_float(rr[j].y);
            #pragma unroll
            for (int k = 0; k < 8; ++k) acc[k] += v * (float)aa[j][k];
        }
    }
    for (; i < e; ++i) {
        int2 r0 = csr[i];
        half8_t a0 = x[((size_t)r0.x << 4) + lane];
        float v0 = __int_as_float(r0.y);
        #pragma unroll
        for (int k = 0; k < 8; ++k) acc[k] += v0 * (float)a0[k];
    }
    half8_t hv;
    #pragma unroll
    for (int k = 0; k < 8; ++k) hv[k] = (_Float16)acc[k];
    h[((size_t)row << 4) + lane] = hv;
}

// last layer: fused epilogue out = fp16(x) + h1 + h2 + acc; 8-edge unroll
__global__ void gather_last_kernel(const int* __restrict__ rowstart,
                                   const int2* __restrict__ csr,
                                   const half8_t* __restrict__ x,      // h2 (gather operand)
                                   const half8_t* __restrict__ x0,
                                   const half8_t* __restrict__ h1,
                                   const half8_t* __restrict__ h2,
                                   float4* __restrict__ out) {
    int gid = blockIdx.x * blockDim.x + threadIdx.x;
    int row = gid >> 4, lane = gid & 15;
    if (row >= NODES) return;
    int s = rowstart[row], e = rowstart[row + 1];
    float acc[8] = {0.f, 0.f, 0.f, 0.f, 0.f, 0.f, 0.f, 0.f};
    int i = s;
    for (; i + 7 < e; i += 8) {
        int2 rr[8];
        #pragma unroll
        for (int j = 0; j < 8; ++j) rr[j] = csr[i + j];
        half8_t aa[8];
        #pragma unroll
        for (int j = 0; j < 8; ++j) aa[j] = x[((size_t)rr[j].x << 4) + lane];
        #pragma unroll
        for (int j = 0; j < 8; ++j) {
            float v = __int_as_float(rr[j].y);
            #pragma unroll
            for (int k = 0; k < 8; ++k) acc[k] += v * (float)aa[j][k];
        }
    }
    for (; i < e; ++i) {
        int2 r0 = csr[i];
        half8_t a0 = x[((size_t)r0.x << 4) + lane];
        float v0 = __int_as_float(r0.y);
        #pragma unroll
        for (int k = 0; k < 8; ++k) acc[k] += v0 * (float)a0[k];
    }
    size_t pidx = ((size_t)row << 4) + lane;
    half8_t xe = x0[pidx], a1 = h1[pidx], a2 = h2[pidx];
    int f4 = row * DIM4 + lane * 2;                  // features lane*8 .. lane*8+7
    if (lane < 13) {
        float4 o0;
        o0.x = acc[0] + (float)xe[0] + (float)a1[0] + (float)a2[0];
        o0.y = acc[1] + (float)xe[1] + (float)a1[1] + (float)a2[1];
        o0.z = acc[2] + (float)xe[2] + (float)a1[2] + (float)a2[2];
        o0.w = acc[3] + (float)xe[3] + (float)a1[3] + (float)a2[3];
        out[f4] = o0;
    }
    if (lane < 12) {                                 // lane 12 covers only feats 96..99
        float4 o1;
        o1.x = acc[4] + (float)xe[4] + (float)a1[4] + (float)a2[4];
        o1.y = acc[5] + (float)xe[5] + (float)a1[5] + (float)a2[5];
        o1.z = acc[6] + (float)xe[6] + (float)a1[6] + (float)a2[6];
        o1.w = acc[7] + (float)xe[7] + (float)a1[7] + (float)a2[7];
        out[f4 + 1] = o1;
    }
}

extern "C" void kernel_launch(void* const* d_in, const int* in_sizes, int n_in,
                              void* d_out, int out_size, void* d_ws, size_t ws_size,
                              hipStream_t stream) {
    const float* emb  = (const float*)d_in[0];
    const int*   rows = (const int*)  d_in[1];
    const int*   cols = (const int*)  d_in[2];
    const float* vals = (const float*)d_in[3];
    const int E = in_sizes[1];

    const size_t ndp_bytes = (size_t)NODES * 128 * sizeof(_Float16);   // 25.6 MB padded

    char* w = (char*)d_ws;
    half8_t* x0p      = (half8_t*)w;  w += ndp_bytes;
    half8_t* h1p      = (half8_t*)w;  w += ndp_bytes;
    half8_t* h2p      = (half8_t*)w;  w += ndp_bytes;                  // aliases staging
    int2*    staging  = (int2*)h2p;                                    // dead after pass2; h2p written after
    int2*    csr      = (int2*)   w;  w += (size_t)E * sizeof(int2);   // 12.8 MB
    int*     rowstart = (int*)    w;  w += (size_t)(NPAD + 256) * sizeof(int);
    int*     bktCount = (int*)    w;  w += 512 * sizeof(int);
    int*     gCur     = (int*)    w;  w += 512 * sizeof(int);          // adjacent to bktCount
    int*     bktStart = (int*)    w;  w += 512 * sizeof(int);
    int*     blkCnt   = (int*)    w;  w += (size_t)NCHUNK * NBUCKETS * sizeof(int); // 800 KB
    // total ~91.0 MB

    float4* out = (float4*)d_out;

    // ---- build CSR ----
    hipMemsetAsync(bktCount, 0, 1024 * sizeof(int), stream);           // bktCount + gCur
    cvt_hist_kernel<<<NCHUNK, 256, 0, stream>>>((const float4*)emb, (half4_t*)x0p,
                                                rows, blkCnt, bktCount, E);
    pass1_kernel<<<NCHUNK, 512, 0, stream>>>(rows, cols, vals, bktCount, blkCnt,
                                             gCur, bktStart, staging, E);
    pass2_kernel<<<NBUCKETS, 512, 0, stream>>>(bktStart, staging, rowstart, csr);

    // ---- 3 gather SpMM layers; last one fuses the output combine ----
    const long long threads = (long long)NODES * 16;
    dim3 gGrid((unsigned)((threads + 255) / 256)), gBlock(256);
    gather_mid4_kernel<<<gGrid, gBlock, 0, stream>>>(rowstart, csr, x0p, h1p);
    gather_mid8_kernel<<<gGrid, gBlock, 0, stream>>>(rowstart, csr, h1p, h2p);
    gather_last_kernel<<<gGrid, gBlock, 0, stream>>>(rowstart, csr, h2p, x0p, h1p, h2p, out);
}

// Round 10
// 361.617 us; speedup vs baseline: 1.3237x; 1.0122x over previous
//
#include <hip/hip_runtime.h>

// out = x + Ax + A^2 x + A^3 x
// Build: 2-level counting sort (391 buckets x 256 rows) -> row-grouped CSR.
//   R10: pass1 scatter rewritten as LDS-sort + coalesced run-write (pass2's own
//   pattern applied inside pass1). Old: one random 8-B write per edge, lines shared
//   across XCDs (R6 showed that pattern costs 8x write amplification). New: block's
//   3200-edge chunk sorted by bucket in LDS, then written as sequential runs into the
//   block's contiguous per-bucket claims -- ~64-B segments, line-private per block.
//   cvt_hist back to R4 1024-grid (R9's 512-grid halved conversion parallelism: null).
// SpMM: pull gather (R4-verified, pinned at ~3.5TB/s scattered-line traffic; 8x|x|
//   L2 fetch is structural on 8 XCDs with uniform-random cols): mid4, mid8, last8.
// N=100000, D=100, E=1600000, layer_num=3 (fixed by setup_inputs)

#define NODES 100000
#define DIM 100
#define DIM4 25                        // float4 chunks per compact fp32 row
#define CH 16                          // 16B fp16 chunks per padded row (128 halves, 256 B)
#define BSHIFT 8
#define NBUCKETS ((NODES + 255) >> 8)  // 391 buckets of 256 rows
#define NPAD (NBUCKETS << BSHIFT)      // 100096
#define P1CHUNK 3200                   // edges per pass1 block (500 blocks at E=1.6M)

typedef _Float16 half4_t __attribute__((ext_vector_type(4)));
typedef _Float16 half8_t __attribute__((ext_vector_type(8)));

// fused: fp32 compact [N][100] -> fp16 padded [N][128]  +  bucket histogram
__global__ void cvt_hist_kernel(const float4* __restrict__ emb, half4_t* __restrict__ x0,
                                const int* __restrict__ rows, int* __restrict__ bktCount, int E) {
    __shared__ int h[NBUCKETS];
    for (int i = threadIdx.x; i < NBUCKETS; i += blockDim.x) h[i] = 0;
    __syncthreads();
    int stride = gridDim.x * blockDim.x;
    int gid = blockIdx.x * blockDim.x + threadIdx.x;
    for (int i = gid; i < NODES * 32; i += stride) {
        int r = i >> 5, c = i & 31;
        half4_t hv;
        if (c < 25) {
            float4 f = emb[r * 25 + c];
            hv.x = (_Float16)f.x; hv.y = (_Float16)f.y;
            hv.z = (_Float16)f.z; hv.w = (_Float16)f.w;
        } else {
            hv.x = (_Float16)0.f; hv.y = (_Float16)0.f;
            hv.z = (_Float16)0.f; hv.w = (_Float16)0.f;
        }
        x0[i] = hv;
    }
    for (int e = gid; e < E; e += stride)
        atomicAdd(&h[rows[e] >> BSHIFT], 1);
    __syncthreads();
    for (int i = threadIdx.x; i < NBUCKETS; i += blockDim.x)
        if (h[i]) atomicAdd(&bktCount[i], h[i]);
}

// pass 1 (512 thr, 500 blocks): count own chunk; global bucket scan (redundant, L2-hot);
// claim per-(block,bucket) regions via gCur; LDS-sort chunk by bucket; write runs.
__global__ void pass1_kernel(const int* __restrict__ rows, const int* __restrict__ cols,
                             const float* __restrict__ vals,
                             const int* __restrict__ bktCount, int* __restrict__ gCur,
                             int* __restrict__ bktStart,
                             int2* __restrict__ staging, int E) {
    __shared__ int2 srt[P1CHUNK];                  // 25.6 KB sorted records
    __shared__ unsigned short bb2[P1CHUNK];        // 6.4 KB bucket of sorted slot
    __shared__ int cnt[NBUCKETS];
    __shared__ int base[NBUCKETS];
    __shared__ int lcur[NBUCKETS];
    __shared__ int bst[NBUCKETS];
    __shared__ int sc[512];
    int t = threadIdx.x;
    for (int i = t; i < NBUCKETS; i += 512) cnt[i] = 0;
    __syncthreads();
    int s = blockIdx.x * P1CHUNK;
    int e = min(E, s + P1CHUNK);
    for (int i = s + t; i < e; i += 512)
        atomicAdd(&cnt[rows[i] >> BSHIFT], 1);
    // global exclusive scan of the 391 bucket counts (1.5 KB, L2-hot)
    int v = (t < NBUCKETS) ? bktCount[t] : 0;
    sc[t] = v;
    __syncthreads();                               // also fences cnt[] counting
    for (int off = 1; off < 512; off <<= 1) {
        int x = (t >= off) ? sc[t - off] : 0;
        __syncthreads();
        sc[t] += x;
        __syncthreads();
    }
    int excl = sc[t] - v;
    if (blockIdx.x == 0) {
        if (t < NBUCKETS) bktStart[t] = excl;
        if (t == 0) bktStart[NBUCKETS] = E;
    }
    if (t < NBUCKETS) {
        int c = cnt[t];
        bst[t] = excl + (c ? atomicAdd(&gCur[t], c) : 0);
    }
    __syncthreads();
    // local exclusive scan of cnt -> base (LDS layout of the sorted chunk)
    int lv = (t < NBUCKETS) ? cnt[t] : 0;
    sc[t] = lv;
    __syncthreads();
    for (int off = 1; off < 512; off <<= 1) {
        int x = (t >= off) ? sc[t - off] : 0;
        __syncthreads();
        sc[t] += x;
        __syncthreads();
    }
    if (t < NBUCKETS) {
        base[t] = sc[t] - lv;
        lcur[t] = sc[t] - lv;
    }
    __syncthreads();
    // scatter chunk into LDS, sorted by bucket
    for (int i = s + t; i < e; i += 512) {
        int r = rows[i];
        int b = r >> BSHIFT;
        int pos = atomicAdd(&lcur[b], 1);
        srt[pos] = make_int2(cols[i] | ((r & 255) << 17), __float_as_int(vals[i]));
        bb2[pos] = (unsigned short)b;
    }
    __syncthreads();
    // coalesced run-write: consecutive slots of a bucket -> consecutive staging addrs
    int n = e - s;
    for (int i = t; i < n; i += 512) {
        int b = bb2[i];
        staging[bst[b] + (i - base[b])] = srt[i];
    }
}

// pass 2 (512 thr): per-bucket counting sort by localrow -> rowstart + CSR
__global__ void pass2_kernel(const int* __restrict__ bktStart, const int2* __restrict__ staging,
                             int* __restrict__ rowstart, int2* __restrict__ csr) {
    __shared__ int hist[256];
    __shared__ int cur[256];
    int b = blockIdx.x, t = threadIdx.x;
    int s = bktStart[b], e = bktStart[b + 1];
    if (t < 256) hist[t] = 0;
    __syncthreads();
    for (int i = s + t; i < e; i += 512)
        atomicAdd(&hist[(staging[i].x >> 17) & 255], 1);
    __syncthreads();
    int v = (t < 256) ? hist[t] : 0;
    if (t < 256) cur[t] = v;
    __syncthreads();
    for (int off = 1; off < 256; off <<= 1) {
        int x = (t >= off && t < 256) ? cur[t - off] : 0;
        __syncthreads();
        if (t < 256) cur[t] += x;
        __syncthreads();
    }
    if (t < 256) {
        int excl = cur[t] - v;
        rowstart[(b << BSHIFT) + t] = s + excl;
        hist[t] = excl;                             // becomes bucket-local cursor
    }
    __syncthreads();
    for (int i = s + t; i < e; i += 512) {
        int2 rec = staging[i];
        int lr = (rec.x >> 17) & 255;
        int p = atomicAdd(&hist[lr], 1);
        csr[s + p] = make_int2(rec.x & 0x1FFFF, rec.y);
    }
}

// pull SpMM: 16 lanes per row, each loads one 16B fp16 chunk (row = 2 aligned 128-B lines)
__global__ void gather_mid4_kernel(const int* __restrict__ rowstart,
                                   const int2* __restrict__ csr,
                                   const half8_t* __restrict__ x,
                                   half8_t* __restrict__ h) {
    int gid = blockIdx.x * blockDim.x + threadIdx.x;
    int row = gid >> 4, lane = gid & 15;
    if (row >= NODES) return;
    int s = rowstart[row], e = rowstart[row + 1];
    float acc[8] = {0.f, 0.f, 0.f, 0.f, 0.f, 0.f, 0.f, 0.f};
    int i = s;
    for (; i + 3 < e; i += 4) {
        int2 r0 = csr[i], r1 = csr[i + 1], r2 = csr[i + 2], r3 = csr[i + 3];
        half8_t a0 = x[((size_t)r0.x << 4) + lane];
        half8_t a1 = x[((size_t)r1.x << 4) + lane];
        half8_t a2 = x[((size_t)r2.x << 4) + lane];
        half8_t a3 = x[((size_t)r3.x << 4) + lane];
        float v0 = __int_as_float(r0.y), v1 = __int_as_float(r1.y);
        float v2 = __int_as_float(r2.y), v3 = __int_as_float(r3.y);
        #pragma unroll
        for (int k = 0; k < 8; ++k)
            acc[k] += v0 * (float)a0[k] + v1 * (float)a1[k]
                    + v2 * (float)a2[k] + v3 * (float)a3[k];
    }
    for (; i < e; ++i) {
        int2 r0 = csr[i];
        half8_t a0 = x[((size_t)r0.x << 4) + lane];
        float v0 = __int_as_float(r0.y);
        #pragma unroll
        for (int k = 0; k < 8; ++k) acc[k] += v0 * (float)a0[k];
    }
    half8_t hv;
    #pragma unroll
    for (int k = 0; k < 8; ++k) hv[k] = (_Float16)acc[k];
    h[((size_t)row << 4) + lane] = hv;
}

// same but 8-edge unroll
__global__ void gather_mid8_kernel(const int* __restrict__ rowstart,
                                   const int2* __restrict__ csr,
                                   const half8_t* __restrict__ x,
                                   half8_t* __restrict__ h) {
    int gid = blockIdx.x * blockDim.x + threadIdx.x;
    int row = gid >> 4, lane = gid & 15;
    if (row >= NODES) return;
    int s = rowstart[row], e = rowstart[row + 1];
    float acc[8] = {0.f, 0.f, 0.f, 0.f, 0.f, 0.f, 0.f, 0.f};
    int i = s;
    for (; i + 7 < e; i += 8) {
        int2 rr[8];
        #pragma unroll
        for (int j = 0; j < 8; ++j) rr[j] = csr[i + j];
        half8_t aa[8];
        #pragma unroll
        for (int j = 0; j < 8; ++j) aa[j] = x[((size_t)rr[j].x << 4) + lane];
        #pragma unroll
        for (int j = 0; j < 8; ++j) {
            float v = __int_as_float(rr[j].y);
            #pragma unroll
            for (int k = 0; k < 8; ++k) acc[k] += v * (float)aa[j][k];
        }
    }
    for (; i < e; ++i) {
        int2 r0 = csr[i];
        half8_t a0 = x[((size_t)r0.x << 4) + lane];
        float v0 = __int_as_float(r0.y);
        #pragma unroll
        for (int k = 0; k < 8; ++k) acc[k] += v0 * (float)a0[k];
    }
    half8_t hv;
    #pragma unroll
    for (int k = 0; k < 8; ++k) hv[k] = (_Float16)acc[k];
    h[((size_t)row << 4) + lane] = hv;
}

// last layer: fused epilogue out = fp16(x) + h1 + h2 + acc; 8-edge unroll
__global__ void gather_last_kernel(const int* __restrict__ rowstart,
                                   const int2* __restrict__ csr,
                                   const half8_t* __restrict__ x,      // h2 (gather operand)
                                   const half8_t* __restrict__ x0,
                                   const half8_t* __restrict__ h1,
                                   const half8_t* __restrict__ h2,
                                   float4* __restrict__ out) {
    int gid = blockIdx.x * blockDim.x + threadIdx.x;
    int row = gid >> 4, lane = gid & 15;
    if (row >= NODES) return;
    int s = rowstart[row], e = rowstart[row + 1];
    float acc[8] = {0.f, 0.f, 0.f, 0.f, 0.f, 0.f, 0.f, 0.f};
    int i = s;
    for (; i + 7 < e; i += 8) {
        int2 rr[8];
        #pragma unroll
        for (int j = 0; j < 8; ++j) rr[j] = csr[i + j];
        half8_t aa[8];
        #pragma unroll
        for (int j = 0; j < 8; ++j) aa[j] = x[((size_t)rr[j].x << 4) + lane];
        #pragma unroll
        for (int j = 0; j < 8; ++j) {
            float v = __int_as_float(rr[j].y);
            #pragma unroll
            for (int k = 0; k < 8; ++k) acc[k] += v * (float)aa[j][k];
        }
    }
    for (; i < e; ++i) {
        int2 r0 = csr[i];
        half8_t a0 = x[((size_t)r0.x << 4) + lane];
        float v0 = __int_as_float(r0.y);
        #pragma unroll
        for (int k = 0; k < 8; ++k) acc[k] += v0 * (float)a0[k];
    }
    size_t pidx = ((size_t)row << 4) + lane;
    half8_t xe = x0[pidx], a1 = h1[pidx], a2 = h2[pidx];
    int f4 = row * DIM4 + lane * 2;                  // features lane*8 .. lane*8+7
    if (lane < 13) {
        float4 o0;
        o0.x = acc[0] + (float)xe[0] + (float)a1[0] + (float)a2[0];
        o0.y = acc[1] + (float)xe[1] + (float)a1[1] + (float)a2[1];
        o0.z = acc[2] + (float)xe[2] + (float)a1[2] + (float)a2[2];
        o0.w = acc[3] + (float)xe[3] + (float)a1[3] + (float)a2[3];
        out[f4] = o0;
    }
    if (lane < 12) {                                 // lane 12 covers only feats 96..99
        float4 o1;
        o1.x = acc[4] + (float)xe[4] + (float)a1[4] + (float)a2[4];
        o1.y = acc[5] + (float)xe[5] + (float)a1[5] + (float)a2[5];
        o1.z = acc[6] + (float)xe[6] + (float)a1[6] + (float)a2[6];
        o1.w = acc[7] + (float)xe[7] + (float)a1[7] + (float)a2[7];
        out[f4 + 1] = o1;
    }
}

extern "C" void kernel_launch(void* const* d_in, const int* in_sizes, int n_in,
                              void* d_out, int out_size, void* d_ws, size_t ws_size,
                              hipStream_t stream) {
    const float* emb  = (const float*)d_in[0];
    const int*   rows = (const int*)  d_in[1];
    const int*   cols = (const int*)  d_in[2];
    const float* vals = (const float*)d_in[3];
    const int E = in_sizes[1];

    const size_t ndp_bytes = (size_t)NODES * 128 * sizeof(_Float16);   // 25.6 MB padded

    char* w = (char*)d_ws;
    half8_t* x0p      = (half8_t*)w;  w += ndp_bytes;
    half8_t* h1p      = (half8_t*)w;  w += ndp_bytes;
    half8_t* h2p      = (half8_t*)w;  w += ndp_bytes;                  // aliases staging
    int2*    staging  = (int2*)h2p;                                    // dead after pass2; h2p written after
    int2*    csr      = (int2*)   w;  w += (size_t)E * sizeof(int2);   // 12.8 MB
    int*     rowstart = (int*)    w;  w += (size_t)(NPAD + 256) * sizeof(int);
    int*     bktCount = (int*)    w;  w += 512 * sizeof(int);
    int*     gCur     = (int*)    w;  w += 512 * sizeof(int);          // adjacent to bktCount
    int*     bktStart = (int*)    w;  w += 512 * sizeof(int);
    // total ~90.2 MB

    float4* out = (float4*)d_out;

    // ---- build CSR ----
    hipMemsetAsync(bktCount, 0, 1024 * sizeof(int), stream);           // bktCount + gCur
    cvt_hist_kernel<<<1024, 256, 0, stream>>>((const float4*)emb, (half4_t*)x0p,
                                              rows, bktCount, E);
    int p1grid = (E + P1CHUNK - 1) / P1CHUNK;                          // 500 at E=1.6M
    pass1_kernel<<<p1grid, 512, 0, stream>>>(rows, cols, vals, bktCount, gCur, bktStart,
                                             staging, E);
    pass2_kernel<<<NBUCKETS, 512, 0, stream>>>(bktStart, staging, rowstart, csr);

    // ---- 3 gather SpMM layers; last one fuses the output combine ----
    const long long threads = (long long)NODES * 16;
    dim3 gGrid((unsigned)((threads + 255) / 256)), gBlock(256);
    gather_mid4_kernel<<<gGrid, gBlock, 0, stream>>>(rowstart, csr, x0p, h1p);
    gather_mid8_kernel<<<gGrid, gBlock, 0, stream>>>(rowstart, csr, h1p, h2p);
    gather_last_kernel<<<gGrid, gBlock, 0, stream>>>(rowstart, csr, h2p, x0p, h1p, h2p, out);
}